// Round 2
// baseline (2702.964 us; speedup 1.0000x reference)
//
#include <hip/hip_runtime.h>
#include <hip/hip_bf16.h>

// FNO spectral layer, B=16, C=64, H=W=256, M=16 modes.
// Pipeline: probe -> k1_dftx -> k2_dfty -> k3_mix -> k4_idfty -> k5_fused
// ws: [0,1KB) flag | X1/G1 @1KB (33.5MB) | Cft (4MB) | Outft (4MB)

#define TWO_PI 6.283185307179586f
typedef __hip_bfloat16 bf16;

__device__ __forceinline__ float ld_in(const void* p, size_t i, int isf32) {
    if (isf32) return ((const float*)p)[i];
    return __bfloat162float(((const bf16*)p)[i]);
}
__device__ __forceinline__ float bfbits2f(unsigned short u) {
    unsigned v = ((unsigned)u) << 16;
    return __uint_as_float(v);
}
__device__ __forceinline__ unsigned clampi(unsigned i, unsigned cap) {
    return i < cap ? i : 0u;
}

// ---- Probe: decide input dtype from raw u16 words of c (safe either way).
__global__ __launch_bounds__(256) void k_probe(const unsigned short* __restrict__ c,
                                               int* __restrict__ flag) {
    __shared__ int cnt;
    if (threadIdx.x == 0) cnt = 0;
    __syncthreads();
    int bad = 0;
    for (int j = 0; j < 4; ++j) {
        unsigned short u = c[threadIdx.x * 4 + j];
        unsigned e = (u >> 7) & 0xFF;
        if (e == 0xFF || e >= 0x87) bad++;   // NaN/Inf or |x| >= 256: impossible for bf16 N(0,1)
    }
    atomicAdd(&cnt, bad);
    __syncthreads();
    if (threadIdx.x == 0) flag[0] = (cnt > 64) ? 1 : 0;   // 1 => inputs are fp32
}

// ---- K1: DFT over x. c[b,i,y,x] -> X1[row][kx], kx=0..15
__global__ __launch_bounds__(256) void k1_dftx(const void* __restrict__ cin,
                                               const int* __restrict__ flag,
                                               float2* __restrict__ X1, unsigned capX1) {
    __shared__ float rows[16][256];
    __shared__ float2 tw[256];
    int t = threadIdx.x;
    int f32 = flag[0];
    float sv, cv;
    sincosf(TWO_PI * (float)t * (1.0f / 256.0f), &sv, &cv);
    tw[t] = make_float2(cv, sv);
    size_t base = (size_t)blockIdx.x * 4096;   // 16 rows * 256
    // vectorized staging: 4096 elems = 4*256 vec4 loads
    if (f32) {
        const float4* p4 = (const float4*)cin + (base >> 2);
#pragma unroll
        for (int q = 0; q < 4; ++q) {
            float4 v = p4[q * 256 + t];
            int row = 4 * q + (t >> 6), col = (t & 63) * 4;
            *(float4*)&rows[row][col] = v;
        }
    } else {
        const short4* p4 = (const short4*)cin + (base >> 2);
#pragma unroll
        for (int q = 0; q < 4; ++q) {
            short4 v = p4[q * 256 + t];
            int row = 4 * q + (t >> 6), col = (t & 63) * 4;
            float4 f;
            f.x = bfbits2f((unsigned short)v.x);
            f.y = bfbits2f((unsigned short)v.y);
            f.z = bfbits2f((unsigned short)v.z);
            f.w = bfbits2f((unsigned short)v.w);
            *(float4*)&rows[row][col] = f;
        }
    }
    __syncthreads();
    int r = t >> 4, kx = t & 15;
    float re = 0.f, im = 0.f;
    for (int x = 0; x < 256; ++x) {
        float v = rows[r][x];
        float2 w = tw[(kx * x) & 255];          // e^{-i th}: (cos, sin), im -= v*sin
        re = fmaf(v, w.x, re);
        im = fmaf(-v, w.y, im);
    }
    unsigned idx = (blockIdx.x * 16u + r) * 16u + kx;
    X1[clampi(idx, capX1)] = make_float2(re, im);
}

// ---- K2: DFT over y. X1[b,i,y,kx] -> Cft[b,i,kyidx,kx], kyidx 0..31
__global__ __launch_bounds__(512) void k2_dfty(const float2* __restrict__ X1,
                                               float2* __restrict__ Cft,
                                               unsigned capX1, unsigned capC) {
    __shared__ float2 tw[256];
    __shared__ float2 xs[4096];  // [y][kx]
    int t = threadIdx.x;
    if (t < 256) {
        float sv, cv;
        sincosf(TWO_PI * (float)t * (1.0f / 256.0f), &sv, &cv);
        tw[t] = make_float2(cv, sv);
    }
    unsigned base = blockIdx.x * 4096u;
    for (int j = 0; j < 8; ++j)
        xs[j * 512 + t] = X1[clampi(base + j * 512 + t, capX1)];
    __syncthreads();
    int kyidx = t >> 4, kx = t & 15;
    int ky = (kyidx < 16) ? kyidx : (224 + kyidx);
    float re = 0.f, im = 0.f;
    for (int y = 0; y < 256; ++y) {
        float2 v = xs[y * 16 + kx];
        float2 w = tw[(ky * y) & 255];
        re += v.x * w.x + v.y * w.y;   // v * e^{-i th}
        im += v.y * w.x - v.x * w.y;
    }
    Cft[clampi(blockIdx.x * 512u + t, capC)] = make_float2(re, im);
}

// ---- K3: mode mixing. block = mode (kyidx*16+kx). Outft[b,o] = sum_i Cft[b,i]*W[i,o]
__global__ __launch_bounds__(256) void k3_mix(const float2* __restrict__ Cft,
                                              const void* __restrict__ w1r, const void* __restrict__ w1i,
                                              const void* __restrict__ w2r, const void* __restrict__ w2i,
                                              float2* __restrict__ Outft,
                                              const int* __restrict__ flag,
                                              unsigned capC, unsigned capO) {
    __shared__ float2 wsm[4096];  // [i*64+o]
    __shared__ float2 cs[1024];   // [b*64+i]
    int t = threadIdx.x;
    int f32 = flag[0];
    int kyidx = blockIdx.x >> 4;
    int moff = ((kyidx < 16) ? kyidx : (kyidx - 16)) * 16 + (blockIdx.x & 15);
    const void* wr = (kyidx < 16) ? w1r : w2r;
    const void* wi = (kyidx < 16) ? w1i : w2i;
    for (int j = 0; j < 16; ++j) {
        int io = j * 256 + t;  // i*64+o
        wsm[io] = make_float2(ld_in(wr, (size_t)io * 256 + moff, f32),
                              ld_in(wi, (size_t)io * 256 + moff, f32));
    }
    for (int j = 0; j < 4; ++j) {
        int bi = j * 256 + t;
        cs[bi] = Cft[clampi((unsigned)bi * 512u + blockIdx.x, capC)];
    }
    __syncthreads();
    int o = t & 63, bq = t >> 6;
    for (int jb = 0; jb < 4; ++jb) {
        int b = bq * 4 + jb;
        float re = 0.f, im = 0.f;
        for (int i = 0; i < 64; ++i) {
            float2 c = cs[b * 64 + i];
            float2 w = wsm[i * 64 + o];
            re += c.x * w.x - c.y * w.y;
            im += c.x * w.y + c.y * w.x;
        }
        Outft[clampi((unsigned)(b * 64 + o) * 512u + blockIdx.x, capO)] = make_float2(re, im);
    }
}

// ---- K4: inverse DFT over y, fold 1/(H*W) and irfft alpha (2x for kx>0).
__global__ __launch_bounds__(256) void k4_idfty(const float2* __restrict__ Outft,
                                                float2* __restrict__ G1,
                                                unsigned capO, unsigned capG) {
    __shared__ float2 tw[256];
    __shared__ float2 fs[512];  // [kyidx][kx]
    int t = threadIdx.x;
    float sv, cv;
    sincosf(TWO_PI * (float)t * (1.0f / 256.0f), &sv, &cv);
    tw[t] = make_float2(cv, sv);
    unsigned base = blockIdx.x * 512u;
    fs[t] = Outft[clampi(base + t, capO)];
    fs[t + 256] = Outft[clampi(base + t + 256, capO)];
    __syncthreads();
    int kx = t & 15, y0 = t >> 4;
    float alpha = ((kx == 0) ? 1.0f : 2.0f) * (1.0f / 65536.0f);
    for (int jj = 0; jj < 16; ++jj) {
        int y = jj * 16 + y0;
        float re = 0.f, im = 0.f;
        for (int k = 0; k < 32; ++k) {
            int ky = (k < 16) ? k : (224 + k);
            float2 f = fs[k * 16 + kx];
            float2 w = tw[(ky * y) & 255];  // e^{+i th}
            re += f.x * w.x - f.y * w.y;
            im += f.x * w.y + f.y * w.x;
        }
        G1[clampi((blockIdx.x * 256u + y) * 16u + kx, capG)] = make_float2(re * alpha, im * alpha);
    }
}

// ---- K5: fused conv + iDFT-x + multiply. 16x16 tile, all 64 oc, 256 threads.
// Thread: ocg=t>>5 (oc = 8j+ocg), pr=( t&31)>>2, pc=t&3 -> 2x4 px patch x 8 oc.
// R2 changes:
//  - 1D grid with XCD-chunked remap: the 16 tx-blocks sharing a (ty,bz) G1 slice
//    land on the SAME XCD -> G1 re-reads hit XCD L2 instead of 8x HBM dup.
//  - register-prefetch double-buffer (T14): issue chunk icc+1 global loads into
//    regs before computing chunk icc; write regs->LDS after the compute barrier.
//  - weights in LDS as [ic][tap][ocg][j]: read as 2x ds_read_b128, broadcast.
//  - input tile stride 20 (16B aligned): rows read as b128+b64 (2-way = free).
__global__ __launch_bounds__(256, 3) void k5_fused(const float2* __restrict__ G1, unsigned capG,
                                                   const void* __restrict__ cin,
                                                   const void* __restrict__ convw,
                                                   const void* __restrict__ convb,
                                                   const int* __restrict__ flag,
                                                   void* __restrict__ out) {
    __shared__ float2 ph[16][16];       // 2KB twiddles for x-iDFT
    __shared__ float xs[8][18][20];     // 11.25KB input chunk (8 ic, 16x16+halo, pad 20)
    __shared__ float wlds[8][9][8][8];  // 18KB weights [ic][tap][ocg][j]
    int t = threadIdx.x;
    int f32 = flag[0];
    // block remap: d = xcd + 8*tx + 128*h, g = xcd + 8*h, ty = g&15, bz = g>>4
    int d = blockIdx.x;
    int tx = (d >> 3) & 15;
    int g  = (d & 7) + ((d >> 7) << 3);
    int ty = g & 15, bz = g >> 4;
    int ocg = t >> 5, pxg = t & 31, pr = pxg >> 2, pc = pxg & 3;

    {
        int kx = t >> 4, xl = t & 15;
        int x = tx * 16 + xl;
        float sv, cv;
        sincosf(TWO_PI * (float)((kx * x) & 255) * (1.0f / 256.0f), &sv, &cv);
        ph[kx][xl] = make_float2(cv, sv);
    }

    float xpre[11], wpre[18];

#define LOAD_REGS(ICC)                                                                  \
    {                                                                                   \
        int icc_ = (ICC);                                                               \
        _Pragma("unroll")                                                               \
        for (int q = 0; q < 11; ++q) {                                                  \
            int idx = q * 256 + t;                                                      \
            if (idx < 2592) {                                                           \
                int i = idx / 324, rem = idx - i * 324;                                 \
                int yy = rem / 18, xx = rem - yy * 18;                                  \
                int yg = (ty * 16 + yy - 1) & 255;                                      \
                int xg = (tx * 16 + xx - 1) & 255;                                      \
                xpre[q] = ld_in(cin, ((size_t)(bz * 64 + icc_ * 8 + i) * 256 + yg) * 256 + xg, f32); \
            }                                                                           \
        }                                                                               \
        _Pragma("unroll")                                                               \
        for (int q = 0; q < 18; ++q) {                                                  \
            int idx = q * 256 + t;                                                      \
            int o = idx / 72, rem = idx - o * 72;                                       \
            wpre[q] = ld_in(convw, (size_t)(o * 64 + icc_ * 8 + rem / 9) * 9 + rem % 9, f32); \
        }                                                                               \
    }

#define WRITE_LDS()                                                                     \
    {                                                                                   \
        _Pragma("unroll")                                                               \
        for (int q = 0; q < 11; ++q) {                                                  \
            int idx = q * 256 + t;                                                      \
            if (idx < 2592) {                                                           \
                int i = idx / 324, rem = idx - i * 324;                                 \
                int yy = rem / 18, xx = rem - yy * 18;                                  \
                xs[i][yy][xx] = xpre[q];                                                \
            }                                                                           \
        }                                                                               \
        _Pragma("unroll")                                                               \
        for (int q = 0; q < 18; ++q) {                                                  \
            int idx = q * 256 + t;                                                      \
            int o = idx / 72, rem = idx - o * 72;                                       \
            wlds[rem / 9][rem % 9][o & 7][o >> 3] = wpre[q];                            \
        }                                                                               \
    }

    float acc[8][8];
#pragma unroll
    for (int j = 0; j < 8; ++j)
#pragma unroll
        for (int p = 0; p < 8; ++p) acc[j][p] = 0.f;

    LOAD_REGS(0);
    WRITE_LDS();

    for (int icc = 0; icc < 8; ++icc) {
        __syncthreads();  // xs/wlds for chunk icc visible
        if (icc < 7) LOAD_REGS(icc + 1);  // global loads in flight under compute
        for (int i = 0; i < 8; ++i) {
            float xr[4][6];
#pragma unroll
            for (int ry = 0; ry < 4; ++ry) {
                const float* rp = &xs[i][2 * pr + ry][4 * pc];
                float4 a = *(const float4*)rp;
                float2 b = *(const float2*)(rp + 4);
                xr[ry][0] = a.x; xr[ry][1] = a.y; xr[ry][2] = a.z;
                xr[ry][3] = a.w; xr[ry][4] = b.x; xr[ry][5] = b.y;
            }
#pragma unroll
            for (int k = 0; k < 9; ++k) {
                const float4* wp = (const float4*)&wlds[i][k][ocg][0];
                float4 w0 = wp[0], w1 = wp[1];
                float wk0 = w0.x, wk1 = w0.y, wk2 = w0.z, wk3 = w0.w;
                float wk4 = w1.x, wk5 = w1.y, wk6 = w1.z, wk7 = w1.w;
                int dy = k / 3, dx = k - dy * 3;
#pragma unroll
                for (int p = 0; p < 8; ++p) {
                    float xv = xr[(p >> 2) + dy][(p & 3) + dx];
                    acc[0][p] = fmaf(wk0, xv, acc[0][p]);
                    acc[1][p] = fmaf(wk1, xv, acc[1][p]);
                    acc[2][p] = fmaf(wk2, xv, acc[2][p]);
                    acc[3][p] = fmaf(wk3, xv, acc[3][p]);
                    acc[4][p] = fmaf(wk4, xv, acc[4][p]);
                    acc[5][p] = fmaf(wk5, xv, acc[5][p]);
                    acc[6][p] = fmaf(wk6, xv, acc[6][p]);
                    acc[7][p] = fmaf(wk7, xv, acc[7][p]);
                }
            }
        }
        __syncthreads();  // all reads of chunk icc done
        if (icc < 7) WRITE_LDS();
    }

    // ---- Epilogue: iDFT over x from G1, fused multiply with (conv + bias), store.
#pragma unroll
    for (int j = 0; j < 8; ++j) {
        int o = 8 * j + ocg;
        float bias = ld_in(convb, o, f32);
#pragma unroll
        for (int ry = 0; ry < 2; ++ry) {
            int y = ty * 16 + 2 * pr + ry;
            unsigned rb = ((unsigned)(bz * 64 + o) * 256u + (unsigned)y) * 16u;
            if (rb + 16u > capG) rb = 0u;
            const float4* gp = (const float4*)(G1 + rb);   // 16 float2 = 8 float4
            float4 fv[8];
#pragma unroll
            for (int m = 0; m < 8; ++m) fv[m] = gp[m];
            float a0 = 0.f, a1 = 0.f, a2 = 0.f, a3 = 0.f;
#pragma unroll
            for (int kx = 0; kx < 16; ++kx) {
                float fre = (kx & 1) ? fv[kx >> 1].z : fv[kx >> 1].x;
                float fim = (kx & 1) ? fv[kx >> 1].w : fv[kx >> 1].y;
                const float4* pp = (const float4*)&ph[kx][4 * pc];
                float4 p01 = pp[0], p23 = pp[1];
                a0 = fmaf(fre, p01.x, a0); a0 = fmaf(-fim, p01.y, a0);
                a1 = fmaf(fre, p01.z, a1); a1 = fmaf(-fim, p01.w, a1);
                a2 = fmaf(fre, p23.x, a2); a2 = fmaf(-fim, p23.y, a2);
                a3 = fmaf(fre, p23.z, a3); a3 = fmaf(-fim, p23.w, a3);
            }
            int pb = ry * 4;
            float v0 = a0 * (acc[j][pb + 0] + bias);
            float v1 = a1 * (acc[j][pb + 1] + bias);
            float v2 = a2 * (acc[j][pb + 2] + bias);
            float v3 = a3 * (acc[j][pb + 3] + bias);
            size_t oidx = (((size_t)(bz * 64 + o) * 256 + y) * 256) + tx * 16 + 4 * pc;
            if (f32) {
                *(float4*)((float*)out + oidx) = make_float4(v0, v1, v2, v3);
            } else {
                bf16* op = (bf16*)out + oidx;
                op[0] = __float2bfloat16(v0);
                op[1] = __float2bfloat16(v1);
                op[2] = __float2bfloat16(v2);
                op[3] = __float2bfloat16(v3);
            }
        }
    }
#undef LOAD_REGS
#undef WRITE_LDS
}

extern "C" void kernel_launch(void* const* d_in, const int* in_sizes, int n_in,
                              void* d_out, int out_size, void* d_ws, size_t ws_size,
                              hipStream_t stream) {
    char* ws = (char*)d_ws;
    int* flag = (int*)ws;  // 1KB header
    const size_t offX1 = 1024;
    const size_t offC  = offX1 + 33554432;   // X1: 4,194,304 float2
    const size_t offO  = offC + 4194304;     // Cft: 524,288 float2
    unsigned capX1, capC, capO;
    {
        size_t a;
        a = (ws_size > offX1 + 8) ? (ws_size - offX1) / 8 : 1;
        capX1 = (unsigned)(a < 4194304 ? a : 4194304);
        a = (ws_size > offC + 8) ? (ws_size - offC) / 8 : 1;
        capC = (unsigned)(a < 524288 ? a : 524288);
        a = (ws_size > offO + 8) ? (ws_size - offO) / 8 : 1;
        capO = (unsigned)(a < 524288 ? a : 524288);
    }
    float2* X1    = (float2*)(ws + offX1);
    float2* Cft   = (float2*)(ws + offC);
    float2* Outft = (float2*)(ws + offO);
    float2* G1    = X1;  // reuse (X1 dead after k2)

    k_probe<<<1, 256, 0, stream>>>((const unsigned short*)d_in[0], flag);
    k1_dftx<<<16384, 256, 0, stream>>>(d_in[0], flag, X1, capX1);
    k2_dfty<<<1024, 512, 0, stream>>>(X1, Cft, capX1, capC);
    k3_mix<<<512, 256, 0, stream>>>(Cft, d_in[1], d_in[2], d_in[3], d_in[4],
                                    Outft, flag, capC, capO);
    k4_idfty<<<1024, 256, 0, stream>>>(Outft, G1, capO, capX1);
    k5_fused<<<4096, 256, 0, stream>>>(G1, capX1, d_in[0], d_in[5], d_in[6], flag, d_out);
}